// Round 6
// baseline (282.016 us; speedup 1.0000x reference)
//
#include <hip/hip_runtime.h>

#define B_DIM 2048
#define IN_DIM 1024
#define OUT_DIM 1024
#define K_KNOTS 20
#define KR (IN_DIM * K_KNOTS)   // 20480 reduction dim
#define OUT_ELEMS (B_DIM * OUT_DIM)
#define KS 8                    // K-split (one slice per XCD)

typedef __bf16 bf16x8 __attribute__((ext_vector_type(8)));
typedef float  f32x4  __attribute__((ext_vector_type(4)));

#define MFMA16(a, b, c) __builtin_amdgcn_mfma_f32_16x16x32_bf16(a, b, c, 0, 0, 0)

__device__ __forceinline__ unsigned short f2bf(float f) {
    unsigned int u = __float_as_uint(f);
    unsigned int r = u + 0x7fffu + ((u >> 16) & 1u);   // RNE; no NaN inputs here
    return (unsigned short)(r >> 16);
}

__device__ __forceinline__ unsigned int pack2(float lo, float hi) {
    return (unsigned int)f2bf(lo) | ((unsigned int)f2bf(hi) << 16);
}

// ============================================================================
// In-register basis computation: 8 consecutive columns [cb, cb+8) of the
// virtual A matrix A[row, c] = exp(-0.5*((x[row, c/20] - knot[c%20])/h)^2).
// cb is a multiple of 8 -> the 8-col run crosses at most one i boundary.
// Formula is kept EXPRESSION-IDENTICAL to the old prep kernel (fma + __expf)
// so results are bit-identical to the materialized-basis path.
// ============================================================================
__device__ __forceinline__ uint4 basis8(const float* __restrict__ x,
                                        int row, int cb,
                                        float t0k, float h, float invh) {
    const int i0  = cb / K_KNOTS;
    const int kk0 = cb - i0 * K_KNOTS;
    const int i1  = i0 + (i0 < IN_DIM - 1 ? 1 : 0);   // clamped (crossing at
    const float xv0 = x[(size_t)row * IN_DIM + i0];   //  i0=1023 cannot occur)
    const float xv1 = x[(size_t)row * IN_DIM + i1];
    float v[8];
#pragma unroll
    for (int j = 0; j < 8; ++j) {
        const int kk   = kk0 + j;
        const bool cr  = kk >= K_KNOTS;
        const float xv = cr ? xv1 : xv0;
        const float kf = (float)(cr ? kk - K_KNOTS : kk);
        const float tt = __builtin_fmaf(kf, h, t0k);
        const float d  = (xv - tt) * invh;
        v[j] = __expf(-0.5f * d * d);
    }
    uint4 o;
    o.x = pack2(v[0], v[1]); o.y = pack2(v[2], v[3]);
    o.z = pack2(v[4], v[5]); o.w = pack2(v[6], v[7]);
    return o;
}

// ============================================================================
// 256x256 / BK=64 / 8-wave GEMM, R3's measured-best 4-phase schedule (86 us,
// MfmaUtil 42%, 0 conflicts) with FUSED STAGING (no prep dispatch):
//   A-tiles: basis computed in-register (exp), ds_write to the SAME
//            swizzled-linear LDS layout gload_lds produced (lane*16B chunks).
//   B-tiles: W loaded as f32 (issued early, T14), packed to bf16 post-MFMA.
// Phases (slot s = t&1):
//   ph1: read a[0..3]k0+b[0..3]k0 (8 ds)                 -> MFMA i0-3 @ k0
//   ph2: read a[0..3]k1+b[0..3]k1 (8 ds)                 -> MFMA i0-3 @ k1
//   ph3: read a[4..7]k0 (4 ds); MFMA i4-7 @ k0; then issue W f32 loads +
//        compute/write A(t+1) (exp hides under MFMA drain, m114)
//   ph4: read a[4..7]k1 (4 ds); MFMA i4-7 @ k1; then pack/write B(t+1)
//   tile end: lgkmcnt(0); barrier   (ds_writes drained; depth-1 prefetch)
// Stage safety: writes target slot s^1, last read in tile t-1 and fenced by
// t-1's end barrier; reads of slot s fenced by this tile's end barrier.
// DO NOT restructure phases without A/B: R1 unbalanced=90us, R2 top-loaded=
// 97us, R3 balanced=86us. Atomic K-split epilogue: 8-XCD same-line ping-pong,
// +31us (R5) -- partials+reduce is the verified epilogue.
// ============================================================================
#define AOFF(s, h) (((s) * 2 + (h)) * 8192)
#define BOFF(s, h) (32768 + ((s) * 2 + (h)) * 8192)

template <int S>
__device__ __forceinline__ void tile_step_f(
        int t, int ntiles,
        const float* __restrict__ x,
        const float* __restrict__ Wf,
        unsigned short* lds,
        f32x4 (&acc)[8][4],
        int m0, int n0, int k0,
        int wave, int lane, int wm, int wn, int r15, int c0, int c1,
        int srow8, int scol,
        float t0k, float h, float invh) {
    const int aB   = S * 16384 + (wm * 128 + r15) * 64;
    const int bB   = 32768 + S * 16384 + (wn * 64 + r15) * 64;
    const int kb1  = k0 + (t + 1) * 64;
    const bool st  = (t + 1 < ntiles);
    const int cbn  = kb1 + scol;                 // next-tile per-lane col base
    const int ldsw = wave * 1024 + lane * 8;     // linear write base (shorts)

    bf16x8 a0[4], a1[4], b0[4], b1[4], s0[4], s1[4];

    // ---------------- phase 1: 8 reads -> MFMA i0..3 @ k0 ----------------
#pragma unroll
    for (int i = 0; i < 4; ++i) a0[i] = *(const bf16x8*)&lds[aB + i * 1024 + c0];
#pragma unroll
    for (int j = 0; j < 4; ++j) b0[j] = *(const bf16x8*)&lds[bB + j * 1024 + c0];
    __builtin_amdgcn_s_barrier();
    asm volatile("s_waitcnt lgkmcnt(0)" ::: "memory");
    __builtin_amdgcn_sched_barrier(0);
    __builtin_amdgcn_s_setprio(1);
#pragma unroll
    for (int i = 0; i < 4; ++i)
#pragma unroll
        for (int j = 0; j < 4; ++j)
            acc[i][j] = MFMA16(a0[i], b0[j], acc[i][j]);
    __builtin_amdgcn_s_setprio(0);

    // ---------------- phase 2: 8 reads -> MFMA i0..3 @ k1 ----------------
#pragma unroll
    for (int i = 0; i < 4; ++i) a1[i] = *(const bf16x8*)&lds[aB + i * 1024 + c1];
#pragma unroll
    for (int j = 0; j < 4; ++j) b1[j] = *(const bf16x8*)&lds[bB + j * 1024 + c1];
    __builtin_amdgcn_s_barrier();
    asm volatile("s_waitcnt lgkmcnt(0)" ::: "memory");
    __builtin_amdgcn_sched_barrier(0);
    __builtin_amdgcn_s_setprio(1);
#pragma unroll
    for (int i = 0; i < 4; ++i)
#pragma unroll
        for (int j = 0; j < 4; ++j)
            acc[i][j] = MFMA16(a1[i], b1[j], acc[i][j]);
    __builtin_amdgcn_s_setprio(0);

    // ------ phase 3: 4 reads -> MFMA i4..7 @ k0; then A(t+1) compute+write ------
#pragma unroll
    for (int i = 0; i < 4; ++i) s0[i] = *(const bf16x8*)&lds[aB + (4 + i) * 1024 + c0];
    __builtin_amdgcn_s_barrier();
    asm volatile("s_waitcnt lgkmcnt(0)" ::: "memory");
    __builtin_amdgcn_sched_barrier(0);
    __builtin_amdgcn_s_setprio(1);
#pragma unroll
    for (int i = 0; i < 4; ++i)
#pragma unroll
        for (int j = 0; j < 4; ++j)
            acc[4 + i][j] = MFMA16(s0[i], b0[j], acc[4 + i][j]);
    __builtin_amdgcn_s_setprio(0);

    f32x4 wA0, wA1, wB0, wB1, wC0, wC1, wD0, wD1;
    if (st) {
        // issue W f32 loads early (consumed in ph4 post-MFMA) -- T14 split
        const float* g0 = Wf + (size_t)(n0 + wave * 16 + srow8) * KR + cbn;
        const float* g1 = g0 + (size_t)8 * KR;
        const float* g2 = g0 + (size_t)128 * KR;
        const float* g3 = g0 + (size_t)136 * KR;
        wA0 = *(const f32x4*)g0;       wA1 = *(const f32x4*)(g0 + 4);
        wB0 = *(const f32x4*)g1;       wB1 = *(const f32x4*)(g1 + 4);
        wC0 = *(const f32x4*)g2;       wC1 = *(const f32x4*)(g2 + 4);
        wD0 = *(const f32x4*)g3;       wD1 = *(const f32x4*)(g3 + 4);
        // A(t+1): basis in-register, write slot S^1 (exp overlaps MFMA drain)
        const int ra = m0 + wave * 16 + srow8;
        uint4 d0 = basis8(x, ra,       cbn, t0k, h, invh);
        uint4 d1 = basis8(x, ra + 8,   cbn, t0k, h, invh);
        uint4 d2 = basis8(x, ra + 128, cbn, t0k, h, invh);
        uint4 d3 = basis8(x, ra + 136, cbn, t0k, h, invh);
        *(uint4*)&lds[AOFF(S ^ 1, 0) + ldsw]       = d0;
        *(uint4*)&lds[AOFF(S ^ 1, 0) + 512 + ldsw] = d1;
        *(uint4*)&lds[AOFF(S ^ 1, 1) + ldsw]       = d2;
        *(uint4*)&lds[AOFF(S ^ 1, 1) + 512 + ldsw] = d3;
    }

    // ------ phase 4: 4 reads -> MFMA i4..7 @ k1; then B(t+1) pack+write ------
#pragma unroll
    for (int i = 0; i < 4; ++i) s1[i] = *(const bf16x8*)&lds[aB + (4 + i) * 1024 + c1];
    __builtin_amdgcn_s_barrier();
    asm volatile("s_waitcnt lgkmcnt(0)" ::: "memory");
    __builtin_amdgcn_sched_barrier(0);
    __builtin_amdgcn_s_setprio(1);
#pragma unroll
    for (int i = 0; i < 4; ++i)
#pragma unroll
        for (int j = 0; j < 4; ++j)
            acc[4 + i][j] = MFMA16(s1[i], b1[j], acc[4 + i][j]);
    __builtin_amdgcn_s_setprio(0);

    if (st) {
        uint4 o0 = make_uint4(pack2(wA0[0], wA0[1]), pack2(wA0[2], wA0[3]),
                              pack2(wA1[0], wA1[1]), pack2(wA1[2], wA1[3]));
        uint4 o1 = make_uint4(pack2(wB0[0], wB0[1]), pack2(wB0[2], wB0[3]),
                              pack2(wB1[0], wB1[1]), pack2(wB1[2], wB1[3]));
        uint4 o2 = make_uint4(pack2(wC0[0], wC0[1]), pack2(wC0[2], wC0[3]),
                              pack2(wC1[0], wC1[1]), pack2(wC1[2], wC1[3]));
        uint4 o3 = make_uint4(pack2(wD0[0], wD0[1]), pack2(wD0[2], wD0[3]),
                              pack2(wD1[0], wD1[1]), pack2(wD1[2], wD1[3]));
        *(uint4*)&lds[BOFF(S ^ 1, 0) + ldsw]       = o0;
        *(uint4*)&lds[BOFF(S ^ 1, 0) + 512 + ldsw] = o1;
        *(uint4*)&lds[BOFF(S ^ 1, 1) + ldsw]       = o2;
        *(uint4*)&lds[BOFF(S ^ 1, 1) + 512 + ldsw] = o3;
    }

    // -------- tile end: drain ds_writes, fence slot swap --------
    asm volatile("s_waitcnt lgkmcnt(0)" ::: "memory");
    __builtin_amdgcn_s_barrier();
}

__global__ void __launch_bounds__(512, 2)
kan_gemmf(const float* __restrict__ x,      // (2048, 1024) f32
          const float* __restrict__ Wf,     // (1024, 20480) f32
          const float* __restrict__ knots,  // (20) f32
          float* __restrict__ part) {       // (KS, 2048, 1024) f32 partials
    __shared__ __align__(16) unsigned short lds[65536];   // 128 KiB

    constexpr int KPBk   = KR / KS;          // 2560
    constexpr int NTILES = KPBk / 64;        // 40

    const int id  = blockIdx.x;
    const int z   = id & 7;                  // K-split slice -> one per XCD
    const int ord = id >> 3;                 // 0..31
    const int mt  = ord & 7;
    const int nt  = ord >> 3;                // 0..3
    const int m0  = mt * 256;
    const int n0  = nt * 256;
    const int k0  = z * KPBk;

    const int tid  = threadIdx.x;
    const int wave = tid >> 6;               // 0..7
    const int lane = tid & 63;
    const int wm   = wave >> 2;              // 0..1 -> wave owns 128 M-rows
    const int wn   = wave & 3;               // 0..3 -> wave owns 64 N-cols

    const int srow8 = lane >> 3;                    // row within 8-row chunk
    const int scol  = ((lane & 7) ^ srow8) * 8;     // swizzled col offset

    const float t0k  = knots[0];
    const float h    = knots[1] - t0k;
    const float invh = 1.0f / h;

    f32x4 acc[8][4];
#pragma unroll
    for (int i = 0; i < 8; ++i)
#pragma unroll
        for (int j = 0; j < 4; ++j) acc[i][j] = (f32x4){0.f, 0.f, 0.f, 0.f};

    const int q   = lane >> 4;
    const int r15 = lane & 15;
    const int r7  = lane & 7;
    const int c0  = (q ^ r7) * 8;            // swizzled 16B slot, kstep 0
    const int c1  = ((4 + q) ^ r7) * 8;      // swizzled 16B slot, kstep 1

    // prologue: compute/stage tile 0 into slot 0
    {
        const int cb0  = k0 + scol;
        const int ldsw = wave * 1024 + lane * 8;
        const int ra   = m0 + wave * 16 + srow8;
        uint4 d0 = basis8(x, ra,       cb0, t0k, h, invh);
        uint4 d1 = basis8(x, ra + 8,   cb0, t0k, h, invh);
        uint4 d2 = basis8(x, ra + 128, cb0, t0k, h, invh);
        uint4 d3 = basis8(x, ra + 136, cb0, t0k, h, invh);
        *(uint4*)&lds[AOFF(0, 0) + ldsw]       = d0;
        *(uint4*)&lds[AOFF(0, 0) + 512 + ldsw] = d1;
        *(uint4*)&lds[AOFF(0, 1) + ldsw]       = d2;
        *(uint4*)&lds[AOFF(0, 1) + 512 + ldsw] = d3;
        const float* g0 = Wf + (size_t)(n0 + wave * 16 + srow8) * KR + cb0;
        const float* g1 = g0 + (size_t)8 * KR;
        const float* g2 = g0 + (size_t)128 * KR;
        const float* g3 = g0 + (size_t)136 * KR;
        f32x4 wA0 = *(const f32x4*)g0, wA1 = *(const f32x4*)(g0 + 4);
        f32x4 wB0 = *(const f32x4*)g1, wB1 = *(const f32x4*)(g1 + 4);
        f32x4 wC0 = *(const f32x4*)g2, wC1 = *(const f32x4*)(g2 + 4);
        f32x4 wD0 = *(const f32x4*)g3, wD1 = *(const f32x4*)(g3 + 4);
        uint4 o0 = make_uint4(pack2(wA0[0], wA0[1]), pack2(wA0[2], wA0[3]),
                              pack2(wA1[0], wA1[1]), pack2(wA1[2], wA1[3]));
        uint4 o1 = make_uint4(pack2(wB0[0], wB0[1]), pack2(wB0[2], wB0[3]),
                              pack2(wB1[0], wB1[1]), pack2(wB1[2], wB1[3]));
        uint4 o2 = make_uint4(pack2(wC0[0], wC0[1]), pack2(wC0[2], wC0[3]),
                              pack2(wC1[0], wC1[1]), pack2(wC1[2], wC1[3]));
        uint4 o3 = make_uint4(pack2(wD0[0], wD0[1]), pack2(wD0[2], wD0[3]),
                              pack2(wD1[0], wD1[1]), pack2(wD1[2], wD1[3]));
        *(uint4*)&lds[BOFF(0, 0) + ldsw]       = o0;
        *(uint4*)&lds[BOFF(0, 0) + 512 + ldsw] = o1;
        *(uint4*)&lds[BOFF(0, 1) + ldsw]       = o2;
        *(uint4*)&lds[BOFF(0, 1) + 512 + ldsw] = o3;
        asm volatile("s_waitcnt lgkmcnt(0)" ::: "memory");
        __builtin_amdgcn_s_barrier();
    }

    for (int tt = 0; tt < NTILES; tt += 2) {
        tile_step_f<0>(tt,     NTILES, x, Wf, lds, acc, m0, n0, k0,
                       wave, lane, wm, wn, r15, c0, c1, srow8, scol,
                       t0k, h, invh);
        tile_step_f<1>(tt + 1, NTILES, x, Wf, lds, acc, m0, n0, k0,
                       wave, lane, wm, wn, r15, c0, c1, srow8, scol,
                       t0k, h, invh);
    }

    // epilogue: partials (verified path); C/D layout col=lane&15
    float* dst = part + (size_t)z * OUT_ELEMS;
#pragma unroll
    for (int i = 0; i < 8; ++i)
#pragma unroll
        for (int j = 0; j < 4; ++j)
#pragma unroll
            for (int r = 0; r < 4; ++r) {
                const int row = m0 + wm * 128 + i * 16 + q * 4 + r;
                const int c   = n0 + wn * 64  + j * 16 + r15;
                dst[(size_t)row * OUT_DIM + c] = acc[i][j][r];
            }
}

// ---------------- reduce KS partial slices -> out ----------------------------
template <int KSr>
__global__ void kan_reduce(const float* __restrict__ part, float* __restrict__ out) {
    const int idx = (blockIdx.x * 256 + threadIdx.x) * 4;
    f32x4 s = *(const f32x4*)(part + idx);
#pragma unroll
    for (int z = 1; z < KSr; ++z)
        s += *(const f32x4*)(part + (size_t)z * OUT_ELEMS + idx);
    *(f32x4*)(out + idx) = s;
}

// ---------------- fallback (ws too small): correctness-only fp32 -------------
__global__ void kan_fallback(const float* __restrict__ x,
                             const float* __restrict__ W,
                             const float* __restrict__ knots,
                             float* __restrict__ out) {
    __shared__ float basis[256 * K_KNOTS];
    const int b = blockIdx.x;
    const int o = blockIdx.y * blockDim.x + threadIdx.x;
    const float invh = 1.0f / (knots[1] - knots[0]);
    const float* w = W + (size_t)o * KR;
    float sum = 0.f;
    for (int i0 = 0; i0 < IN_DIM; i0 += 256) {
        __syncthreads();
        for (int idx = threadIdx.x; idx < 256 * K_KNOTS; idx += blockDim.x) {
            const int i = i0 + idx / K_KNOTS;
            const int k = idx % K_KNOTS;
            const float d = (x[(size_t)b * IN_DIM + i] - knots[k]) * invh;
            basis[idx] = __expf(-0.5f * d * d);
        }
        __syncthreads();
        for (int r = 0; r < 256 * K_KNOTS; ++r)
            sum += basis[r] * w[(size_t)i0 * K_KNOTS + r];
    }
    out[(size_t)b * OUT_DIM + o] = sum;
}

extern "C" void kernel_launch(void* const* d_in, const int* in_sizes, int n_in,
                              void* d_out, int out_size, void* d_ws, size_t ws_size,
                              hipStream_t stream) {
    const float* x     = (const float*)d_in[0];
    const float* W     = (const float*)d_in[1];
    const float* knots = (const float*)d_in[2];
    float* out = (float*)d_out;

    const size_t part_bytes = (size_t)KS * OUT_ELEMS * 4;           // 64 MiB
    float* part = (float*)d_ws;

    if (ws_size >= part_bytes) {
        // main path: fused-staging gemm (no prep!) + reduce. 2 dispatches.
        kan_gemmf<<<dim3(256), dim3(512), 0, stream>>>(x, W, knots, part);
        kan_reduce<KS><<<dim3(OUT_ELEMS / (256 * 4)), dim3(256), 0, stream>>>(part, out);
    } else {
        kan_fallback<<<dim3(B_DIM, OUT_DIM / 256), dim3(256), 0, stream>>>(x, W, knots, out);
    }
}

// Round 7
// 272.064 us; speedup vs baseline: 1.0366x; 1.0366x over previous
//
#include <hip/hip_runtime.h>

#define B_DIM 2048
#define IN_DIM 1024
#define OUT_DIM 1024
#define K_KNOTS 20
#define KR (IN_DIM * K_KNOTS)   // 20480 reduction dim
#define OUT_ELEMS (B_DIM * OUT_DIM)
#define KS 8                    // K-split (one slice per XCD)

// ---- prep sizing: paired-quad threads, 16B stores ----
#define NPAIRS (B_DIM * IN_DIM * 5 / 2)           // 5,242,880 threads
#define NB_PREP_BLK (NPAIRS / 256)                // 20480 blocks

typedef __bf16 bf16x8 __attribute__((ext_vector_type(8)));
typedef float  f32x4  __attribute__((ext_vector_type(4)));

#define MFMA16(a, b, c) __builtin_amdgcn_mfma_f32_16x16x32_bf16(a, b, c, 0, 0, 0)

__device__ __forceinline__ unsigned short f2bf(float f) {
    unsigned int u = __float_as_uint(f);
    unsigned int r = u + 0x7fffu + ((u >> 16) & 1u);   // RNE; no NaN inputs here
    return (unsigned short)(r >> 16);
}

__device__ __forceinline__ unsigned int pack2(float lo, float hi) {
    return (unsigned int)f2bf(lo) | ((unsigned int)f2bf(hi) << 16);
}

// HW packed f32->bf16 (RNE), 1 inst per 2 elems (no builtin on gfx950 -> asm)
__device__ __forceinline__ unsigned int cvtpk(float lo, float hi) {
    unsigned int r;
    asm("v_cvt_pk_bf16_f32 %0, %1, %2" : "=v"(r) : "v"(lo), "v"(hi));
    return r;
}

__device__ __forceinline__ void async_load16(const void* g, void* l) {
    __builtin_amdgcn_global_load_lds(
        (const __attribute__((address_space(1))) void*)g,
        (__attribute__((address_space(3))) void*)l,
        16, 0, 0);
}

// ============================================================================
// prep: basis ONLY (W is consumed as f32 by the gemm now -- R6 lesson: the
// A-side exp must NOT live in the gemm critical path, but the W bf16
// conversion pass was pure waste: 120 MiB RT eliminated).
// Paired-quad threads: 8 knots -> one uint4 (16 B) store, 1-2 x loads.
// Formula EXPRESSION-IDENTICAL to all prior rounds (fma + __expf).
// ============================================================================
__global__ void __launch_bounds__(256) prep_kernel(
        const float* __restrict__ x,
        const float* __restrict__ knots,
        uint4* __restrict__ basis_out) {
    const unsigned int p  = blockIdx.x * 256 + threadIdx.x;   // pair index
    const unsigned int n0 = 2 * p;                            // first quad
    const unsigned int q0  = n0 % 5u;
    const unsigned int bi0 = n0 / 5u;
    const float t0   = knots[0];
    const float h    = knots[1] - t0;
    const float invh = 1.0f / h;

    const bool cross = (q0 == 4u);
    const unsigned int bi1 = bi0 + (cross ? 1u : 0u);
    const float xv0 = x[bi0];
    const float xv1 = x[bi1];                  // == xv0 when !cross (cached)
    const float kA = (float)(4u * q0);
    const float kB = cross ? 0.f : kA + 4.f;

    float v[8];
#pragma unroll
    for (int j = 0; j < 4; ++j) {
        float t = __builtin_fmaf(kA + (float)j, h, t0);
        float d = (xv0 - t) * invh;
        v[j] = __expf(-0.5f * d * d);
    }
#pragma unroll
    for (int j = 0; j < 4; ++j) {
        float t = __builtin_fmaf(kB + (float)j, h, t0);
        float d = (xv1 - t) * invh;
        v[4 + j] = __expf(-0.5f * d * d);
    }
    uint4 o;
    o.x = pack2(v[0], v[1]); o.y = pack2(v[2], v[3]);
    o.z = pack2(v[4], v[5]); o.w = pack2(v[6], v[7]);
    basis_out[p] = o;
}

// ============================================================================
// 256x256 / BK=64 / 8-wave GEMM, R3's measured-best 4-phase schedule (86 us,
// MfmaUtil 42%, 0 conflicts). A staged via global_load_lds from materialized
// basis (UNCHANGED from R3). B staged from f32 W via reg-staging:
//   ph3 (post-MFMA): issue 8x f32x4 W loads (T14 early-issue)
//   ph4 (post-MFMA): 16x v_cvt_pk_bf16_f32 + 4x ds_write_b128 to the SAME
//                    swizzled-linear layout gload_lds produced
//   tile end: vmcnt(0) [A stages] + lgkmcnt(0) [B writes]; barrier
// WAR safety: B writes hit slot s^1, last read in tile t-1, fenced by its end
// barrier. DO NOT restructure phases without A/B: R1 unbalanced=90us, R2
// top-loaded=97us, R3 balanced=86us, R6 A-fused(exp in path)=187us.
// Atomic K-split epilogue: 8-XCD same-line ping-pong, +31us (R5) -- partials+
// reduce is the verified epilogue.
// ============================================================================
#define AOFF(s, h) (((s) * 2 + (h)) * 8192)
#define BOFF(s, h) (32768 + ((s) * 2 + (h)) * 8192)

template <int S>
__device__ __forceinline__ void tile_step(
        int t, int ntiles,
        const unsigned short* __restrict__ Ab,
        const float* __restrict__ Wf,
        unsigned short* lds,
        f32x4 (&acc)[8][4],
        int m0, int n0, int k0,
        int wave, int lane, int wm, int wn, int r15, int c0, int c1,
        int srow8, int scol) {
    const int aB   = S * 16384 + (wm * 128 + r15) * 64;
    const int bB   = 32768 + S * 16384 + (wn * 64 + r15) * 64;
    const int kb1  = k0 + (t + 1) * 64;
    const bool st  = (t + 1 < ntiles);
    const int ldsw = wave * 1024 + lane * 8;     // linear write base (shorts)

    bf16x8 a0[4], a1[4], b0[4], b1[4], s0[4], s1[4];

    // ---------------- phase 1: 8 reads -> MFMA i0..3 @ k0 ----------------
#pragma unroll
    for (int i = 0; i < 4; ++i) a0[i] = *(const bf16x8*)&lds[aB + i * 1024 + c0];
#pragma unroll
    for (int j = 0; j < 4; ++j) b0[j] = *(const bf16x8*)&lds[bB + j * 1024 + c0];
    __builtin_amdgcn_s_barrier();
    asm volatile("s_waitcnt lgkmcnt(0)" ::: "memory");
    __builtin_amdgcn_sched_barrier(0);
    __builtin_amdgcn_s_setprio(1);
#pragma unroll
    for (int i = 0; i < 4; ++i)
#pragma unroll
        for (int j = 0; j < 4; ++j)
            acc[i][j] = MFMA16(a0[i], b0[j], acc[i][j]);
    __builtin_amdgcn_s_setprio(0);

    // ---------------- phase 2: 8 reads -> MFMA i0..3 @ k1 ----------------
#pragma unroll
    for (int i = 0; i < 4; ++i) a1[i] = *(const bf16x8*)&lds[aB + i * 1024 + c1];
#pragma unroll
    for (int j = 0; j < 4; ++j) b1[j] = *(const bf16x8*)&lds[bB + j * 1024 + c1];
    __builtin_amdgcn_s_barrier();
    asm volatile("s_waitcnt lgkmcnt(0)" ::: "memory");
    __builtin_amdgcn_sched_barrier(0);
    __builtin_amdgcn_s_setprio(1);
#pragma unroll
    for (int i = 0; i < 4; ++i)
#pragma unroll
        for (int j = 0; j < 4; ++j)
            acc[i][j] = MFMA16(a1[i], b1[j], acc[i][j]);
    __builtin_amdgcn_s_setprio(0);

    // ---- phase 3: 4 reads + stage A(t+1) + issue W f32 loads -> MFMA i4..7 @ k0 ----
#pragma unroll
    for (int i = 0; i < 4; ++i) s0[i] = *(const bf16x8*)&lds[aB + (4 + i) * 1024 + c0];
    f32x4 w0, w1, w2, w3, w4, w5, w6, w7;
    if (st) {
        const unsigned short* ga = Ab + (size_t)(m0 + wave * 16 + srow8) * KR + kb1 + scol;
        async_load16(ga,                   &lds[AOFF(S ^ 1, 0) + wave * 1024]);
        async_load16(ga + (size_t)8 * KR,  &lds[AOFF(S ^ 1, 0) + wave * 1024 + 512]);
        const unsigned short* ga1 = ga + (size_t)128 * KR;
        async_load16(ga1,                  &lds[AOFF(S ^ 1, 1) + wave * 1024]);
        async_load16(ga1 + (size_t)8 * KR, &lds[AOFF(S ^ 1, 1) + wave * 1024 + 512]);
        const float* g0 = Wf + (size_t)(n0 + wave * 16 + srow8) * KR + kb1 + scol;
        const float* g1 = g0 + (size_t)8 * KR;
        const float* g2 = g0 + (size_t)128 * KR;
        const float* g3 = g0 + (size_t)136 * KR;
        w0 = *(const f32x4*)g0; w1 = *(const f32x4*)(g0 + 4);
        w2 = *(const f32x4*)g1; w3 = *(const f32x4*)(g1 + 4);
        w4 = *(const f32x4*)g2; w5 = *(const f32x4*)(g2 + 4);
        w6 = *(const f32x4*)g3; w7 = *(const f32x4*)(g3 + 4);
    }
    __builtin_amdgcn_s_barrier();
    asm volatile("s_waitcnt lgkmcnt(0)" ::: "memory");
    __builtin_amdgcn_sched_barrier(0);
    __builtin_amdgcn_s_setprio(1);
#pragma unroll
    for (int i = 0; i < 4; ++i)
#pragma unroll
        for (int j = 0; j < 4; ++j)
            acc[4 + i][j] = MFMA16(s0[i], b0[j], acc[4 + i][j]);
    __builtin_amdgcn_s_setprio(0);

    // ------ phase 4: 4 reads -> MFMA i4..7 @ k1; then pack+write B(t+1) ------
#pragma unroll
    for (int i = 0; i < 4; ++i) s1[i] = *(const bf16x8*)&lds[aB + (4 + i) * 1024 + c1];
    __builtin_amdgcn_s_barrier();
    asm volatile("s_waitcnt lgkmcnt(0)" ::: "memory");
    __builtin_amdgcn_sched_barrier(0);
    __builtin_amdgcn_s_setprio(1);
#pragma unroll
    for (int i = 0; i < 4; ++i)
#pragma unroll
        for (int j = 0; j < 4; ++j)
            acc[4 + i][j] = MFMA16(s1[i], b1[j], acc[4 + i][j]);
    __builtin_amdgcn_s_setprio(0);

    if (st) {
        uint4 o0 = make_uint4(cvtpk(w0[0], w0[1]), cvtpk(w0[2], w0[3]),
                              cvtpk(w1[0], w1[1]), cvtpk(w1[2], w1[3]));
        uint4 o1 = make_uint4(cvtpk(w2[0], w2[1]), cvtpk(w2[2], w2[3]),
                              cvtpk(w3[0], w3[1]), cvtpk(w3[2], w3[3]));
        uint4 o2 = make_uint4(cvtpk(w4[0], w4[1]), cvtpk(w4[2], w4[3]),
                              cvtpk(w5[0], w5[1]), cvtpk(w5[2], w5[3]));
        uint4 o3 = make_uint4(cvtpk(w6[0], w6[1]), cvtpk(w6[2], w6[3]),
                              cvtpk(w7[0], w7[1]), cvtpk(w7[2], w7[3]));
        *(uint4*)&lds[BOFF(S ^ 1, 0) + ldsw]       = o0;
        *(uint4*)&lds[BOFF(S ^ 1, 0) + 512 + ldsw] = o1;
        *(uint4*)&lds[BOFF(S ^ 1, 1) + ldsw]       = o2;
        *(uint4*)&lds[BOFF(S ^ 1, 1) + 512 + ldsw] = o3;
    }

    // ---- tile end: drain A gload_lds (vmcnt) + B ds_writes (lgkm); fence ----
    if (st) asm volatile("s_waitcnt vmcnt(0)" ::: "memory");
    asm volatile("s_waitcnt lgkmcnt(0)" ::: "memory");
    __builtin_amdgcn_s_barrier();
}

__global__ void __launch_bounds__(512, 2)
kan_gemm8(const unsigned short* __restrict__ Ab,  // (2048, 20480) bf16 basis
          const float* __restrict__ Wf,           // (1024, 20480) f32 W
          float* __restrict__ part) {             // (KS, 2048, 1024) partials
    __shared__ __align__(16) unsigned short lds[65536];   // 128 KiB

    constexpr int KPBk   = KR / KS;          // 2560
    constexpr int NTILES = KPBk / 64;        // 40

    const int id  = blockIdx.x;
    const int z   = id & 7;                  // K-split slice -> one per XCD
    const int ord = id >> 3;                 // 0..31
    const int mt  = ord & 7;
    const int nt  = ord >> 3;                // 0..3
    const int m0  = mt * 256;
    const int n0  = nt * 256;
    const int k0  = z * KPBk;

    const int tid  = threadIdx.x;
    const int wave = tid >> 6;               // 0..7
    const int lane = tid & 63;
    const int wm   = wave >> 2;              // 0..1 -> wave owns 128 M-rows
    const int wn   = wave & 3;               // 0..3 -> wave owns 64 N-cols

    const int srow8 = lane >> 3;                    // row within 8-row chunk
    const int scol  = ((lane & 7) ^ srow8) * 8;     // pre-swizzled col offset

    f32x4 acc[8][4];
#pragma unroll
    for (int i = 0; i < 8; ++i)
#pragma unroll
        for (int j = 0; j < 4; ++j) acc[i][j] = (f32x4){0.f, 0.f, 0.f, 0.f};

    const int q   = lane >> 4;
    const int r15 = lane & 15;
    const int r7  = lane & 7;
    const int c0  = (q ^ r7) * 8;            // swizzled 16B slot, kstep 0
    const int c1  = ((4 + q) ^ r7) * 8;      // swizzled 16B slot, kstep 1

    // prologue: stage tile 0 into slot 0 (A via gload_lds, B via f32+cvtpk)
    {
        const int ldsw = wave * 1024 + lane * 8;
        const unsigned short* ga = Ab + (size_t)(m0 + wave * 16 + srow8) * KR + k0 + scol;
        async_load16(ga,                   &lds[AOFF(0, 0) + wave * 1024]);
        async_load16(ga + (size_t)8 * KR,  &lds[AOFF(0, 0) + wave * 1024 + 512]);
        const unsigned short* ga1 = ga + (size_t)128 * KR;
        async_load16(ga1,                  &lds[AOFF(0, 1) + wave * 1024]);
        async_load16(ga1 + (size_t)8 * KR, &lds[AOFF(0, 1) + wave * 1024 + 512]);
        const float* g0 = Wf + (size_t)(n0 + wave * 16 + srow8) * KR + k0 + scol;
        const float* g1 = g0 + (size_t)8 * KR;
        const float* g2 = g0 + (size_t)128 * KR;
        const float* g3 = g0 + (size_t)136 * KR;
        f32x4 w0 = *(const f32x4*)g0, w1 = *(const f32x4*)(g0 + 4);
        f32x4 w2 = *(const f32x4*)g1, w3 = *(const f32x4*)(g1 + 4);
        f32x4 w4 = *(const f32x4*)g2, w5 = *(const f32x4*)(g2 + 4);
        f32x4 w6 = *(const f32x4*)g3, w7 = *(const f32x4*)(g3 + 4);
        uint4 o0 = make_uint4(cvtpk(w0[0], w0[1]), cvtpk(w0[2], w0[3]),
                              cvtpk(w1[0], w1[1]), cvtpk(w1[2], w1[3]));
        uint4 o1 = make_uint4(cvtpk(w2[0], w2[1]), cvtpk(w2[2], w2[3]),
                              cvtpk(w3[0], w3[1]), cvtpk(w3[2], w3[3]));
        uint4 o2 = make_uint4(cvtpk(w4[0], w4[1]), cvtpk(w4[2], w4[3]),
                              cvtpk(w5[0], w5[1]), cvtpk(w5[2], w5[3]));
        uint4 o3 = make_uint4(cvtpk(w6[0], w6[1]), cvtpk(w6[2], w6[3]),
                              cvtpk(w7[0], w7[1]), cvtpk(w7[2], w7[3]));
        *(uint4*)&lds[BOFF(0, 0) + ldsw]       = o0;
        *(uint4*)&lds[BOFF(0, 0) + 512 + ldsw] = o1;
        *(uint4*)&lds[BOFF(0, 1) + ldsw]       = o2;
        *(uint4*)&lds[BOFF(0, 1) + 512 + ldsw] = o3;
        asm volatile("s_waitcnt vmcnt(0) lgkmcnt(0)" ::: "memory");
        __builtin_amdgcn_s_barrier();
    }

    for (int tt = 0; tt < NTILES; tt += 2) {
        tile_step<0>(tt,     NTILES, Ab, Wf, lds, acc, m0, n0, k0,
                     wave, lane, wm, wn, r15, c0, c1, srow8, scol);
        tile_step<1>(tt + 1, NTILES, Ab, Wf, lds, acc, m0, n0, k0,
                     wave, lane, wm, wn, r15, c0, c1, srow8, scol);
    }

    // epilogue: partials (verified path); C/D layout col=lane&15
    float* dst = part + (size_t)z * OUT_ELEMS;
#pragma unroll
    for (int i = 0; i < 8; ++i)
#pragma unroll
        for (int j = 0; j < 4; ++j)
#pragma unroll
            for (int r = 0; r < 4; ++r) {
                const int row = m0 + wm * 128 + i * 16 + q * 4 + r;
                const int c   = n0 + wn * 64  + j * 16 + r15;
                dst[(size_t)row * OUT_DIM + c] = acc[i][j][r];
            }
}

// ---------------- reduce KS partial slices -> out ----------------------------
template <int KSr>
__global__ void kan_reduce(const float* __restrict__ part, float* __restrict__ out) {
    const int idx = (blockIdx.x * 256 + threadIdx.x) * 4;
    f32x4 s = *(const f32x4*)(part + idx);
#pragma unroll
    for (int z = 1; z < KSr; ++z)
        s += *(const f32x4*)(part + (size_t)z * OUT_ELEMS + idx);
    *(f32x4*)(out + idx) = s;
}

// ---------------- fallback (ws too small): correctness-only fp32 -------------
__global__ void kan_fallback(const float* __restrict__ x,
                             const float* __restrict__ W,
                             const float* __restrict__ knots,
                             float* __restrict__ out) {
    __shared__ float basis[256 * K_KNOTS];
    const int b = blockIdx.x;
    const int o = blockIdx.y * blockDim.x + threadIdx.x;
    const float invh = 1.0f / (knots[1] - knots[0]);
    const float* w = W + (size_t)o * KR;
    float sum = 0.f;
    for (int i0 = 0; i0 < IN_DIM; i0 += 256) {
        __syncthreads();
        for (int idx = threadIdx.x; idx < 256 * K_KNOTS; idx += blockDim.x) {
            const int i = i0 + idx / K_KNOTS;
            const int k = idx % K_KNOTS;
            const float d = (x[(size_t)b * IN_DIM + i] - knots[k]) * invh;
            basis[idx] = __expf(-0.5f * d * d);
        }
        __syncthreads();
        for (int r = 0; r < 256 * K_KNOTS; ++r)
            sum += basis[r] * w[(size_t)i0 * K_KNOTS + r];
    }
    out[(size_t)b * OUT_DIM + o] = sum;
}

extern "C" void kernel_launch(void* const* d_in, const int* in_sizes, int n_in,
                              void* d_out, int out_size, void* d_ws, size_t ws_size,
                              hipStream_t stream) {
    const float* x     = (const float*)d_in[0];
    const float* W     = (const float*)d_in[1];
    const float* knots = (const float*)d_in[2];
    float* out = (float*)d_out;

    const size_t basis_bytes = (size_t)B_DIM * KR * 2;              // 80 MiB
    const size_t part_bytes  = (size_t)KS * OUT_ELEMS * 4;          // 64 MiB

    unsigned short* Ab = (unsigned short*)d_ws;
    float* part = (float*)((char*)d_ws + basis_bytes);

    if (ws_size >= basis_bytes + part_bytes) {
        // main path: basis-only prep + f32-B gemm + reduce. 3 dispatches.
        prep_kernel<<<dim3(NB_PREP_BLK), dim3(256), 0, stream>>>(
            x, knots, (uint4*)Ab);
        kan_gemm8<<<dim3(256), dim3(512), 0, stream>>>(Ab, W, part);
        kan_reduce<KS><<<dim3(OUT_ELEMS / (256 * 4)), dim3(256), 0, stream>>>(part, out);
    } else {
        kan_fallback<<<dim3(B_DIM, OUT_DIM / 256), dim3(256), 0, stream>>>(x, W, knots, out);
    }
}

// Round 8
// 246.177 us; speedup vs baseline: 1.1456x; 1.1052x over previous
//
#include <hip/hip_runtime.h>

#define B_DIM 2048
#define IN_DIM 1024
#define OUT_DIM 1024
#define K_KNOTS 20
#define KR (IN_DIM * K_KNOTS)   // 20480 reduction dim
#define OUT_ELEMS (B_DIM * OUT_DIM)
#define KS 8                    // K-split (one slice per XCD)

// ---- prep sizing ----
#define NPAIRS (B_DIM * IN_DIM * 5 / 2)           // 5,242,880 basis-pair threads
#define NB_BASIS_BLK (NPAIRS / 256)               // 20480 blocks
#define NW4 (OUT_DIM * KR / 8)                    // 2,621,440 uint4 outputs
#define NB_W_BLK (NW4 / 256)                      // 10240 blocks

typedef __bf16 bf16x8 __attribute__((ext_vector_type(8)));
typedef float  f32x4  __attribute__((ext_vector_type(4)));

#define MFMA16(a, b, c) __builtin_amdgcn_mfma_f32_16x16x32_bf16(a, b, c, 0, 0, 0)

__device__ __forceinline__ unsigned short f2bf(float f) {
    unsigned int u = __float_as_uint(f);
    unsigned int r = u + 0x7fffu + ((u >> 16) & 1u);   // RNE; no NaN inputs here
    return (unsigned short)(r >> 16);
}

__device__ __forceinline__ unsigned int pack2(float lo, float hi) {
    return (unsigned int)f2bf(lo) | ((unsigned int)f2bf(hi) << 16);
}

__device__ __forceinline__ void async_load16(const void* g, void* l) {
    __builtin_amdgcn_global_load_lds(
        (const __attribute__((address_space(1))) void*)g,
        (__attribute__((address_space(3))) void*)l,
        16, 0, 0);
}

// ============================================================================
// prep: basis bf16 (paired-quad threads, 16B stores -- R7's measured ~31us)
// + W fp32->bf16 (R3's 16B-load/store pass). One dispatch, two block ranges.
// LEDGER (do not revisit): A-exp fused in gemm = 187us (R6); B-f32 fused in
// gemm = 146us gemm + doubled B fetch (R7). Materialized bf16 A and B with
// gload_lds staging is the measured optimum (86us gemm, R3).
// ============================================================================
__global__ void __launch_bounds__(256) prep_kernel(
        const float* __restrict__ x,
        const float4* __restrict__ Wsrc,
        const float* __restrict__ knots,
        uint4* __restrict__ basis_out,
        uint4* __restrict__ w_out) {
    if (blockIdx.x < NB_BASIS_BLK) {
        const unsigned int p  = blockIdx.x * 256 + threadIdx.x;   // pair index
        const unsigned int n0 = 2 * p;                            // first quad
        const unsigned int q0  = n0 % 5u;
        const unsigned int bi0 = n0 / 5u;
        const float t0   = knots[0];
        const float h    = knots[1] - t0;
        const float invh = 1.0f / h;

        const bool cross = (q0 == 4u);
        const unsigned int bi1 = bi0 + (cross ? 1u : 0u);
        const float xv0 = x[bi0];
        const float xv1 = x[bi1];              // == xv0 when !cross (cached)
        const float kA = (float)(4u * q0);
        const float kB = cross ? 0.f : kA + 4.f;

        float v[8];
#pragma unroll
        for (int j = 0; j < 4; ++j) {
            float t = __builtin_fmaf(kA + (float)j, h, t0);
            float d = (xv0 - t) * invh;
            v[j] = __expf(-0.5f * d * d);
        }
#pragma unroll
        for (int j = 0; j < 4; ++j) {
            float t = __builtin_fmaf(kB + (float)j, h, t0);
            float d = (xv1 - t) * invh;
            v[4 + j] = __expf(-0.5f * d * d);
        }
        uint4 o;
        o.x = pack2(v[0], v[1]); o.y = pack2(v[2], v[3]);
        o.z = pack2(v[4], v[5]); o.w = pack2(v[6], v[7]);
        basis_out[p] = o;
    } else {
        unsigned int t = (blockIdx.x - NB_BASIS_BLK) * 256 + threadIdx.x;
        float4 a = Wsrc[2 * t];
        float4 b = Wsrc[2 * t + 1];
        uint4 o;
        o.x = pack2(a.x, a.y);
        o.y = pack2(a.z, a.w);
        o.z = pack2(b.x, b.y);
        o.w = pack2(b.z, b.w);
        w_out[t] = o;
    }
}

// ============================================================================
// 256x256 / BK=64 / 8-wave GEMM: R3's measured-best 4-phase schedule
// (86 us, MfmaUtil 42%, 0 bank conflicts). BYTE-IDENTICAL to R3 -- both A and
// B staged via global_load_lds from materialized bf16, swizzled-linear LDS.
//   ph1: read a[0..3]k0 + b[0..3]k0 (8 ds)                 -> MFMA i0-3 @ k0
//   ph2: read a[0..3]k1 + b[0..3]k1 (8 ds)                 -> MFMA i0-3 @ k1
//   ph3: read a[4..7]k0 (4 ds) + stage A(t+1) h0,h1        -> MFMA i4-7 @ k0
//   ph4: read a[4..7]k1 (4 ds) + stage B(t+1) h0,h1        -> MFMA i4-7 @ k1
//   tile end: vmcnt(0); barrier   (depth-1 prefetch)
// Phase = [reads; stages; s_barrier; lgkmcnt(0); setprio(1) MFMA setprio(0)].
// DO NOT restructure without A/B: R1 unbalanced=90, R2 top-loaded=97,
// R3 balanced=86, R6 A-fused=187, R7 B-f32=146. Atomic K-split: +31us (R5).
// ============================================================================
#define AOFF(s, h) (((s) * 2 + (h)) * 8192)
#define BOFF(s, h) (32768 + ((s) * 2 + (h)) * 8192)

template <int S>
__device__ __forceinline__ void tile_step(
        int t, int ntiles,
        const unsigned short* __restrict__ Ab,
        const unsigned short* __restrict__ Bb,
        unsigned short* lds,
        f32x4 (&acc)[8][4],
        int m0, int n0, int k0,
        int wave, int wm, int wn, int r15, int c0, int c1,
        int srow8, int scol) {
    const int aB  = S * 16384 + (wm * 128 + r15) * 64;
    const int bB  = 32768 + S * 16384 + (wn * 64 + r15) * 64;
    const int kb1 = k0 + (t + 1) * 64;
    const bool st = (t + 1 < ntiles);

    auto stage = [&](const unsigned short* __restrict__ src, int grow, int kb, int lbase) {
        const unsigned short* g = src + (size_t)(grow + wave * 16 + srow8) * KR + kb + scol;
        async_load16(g,                  &lds[lbase + wave * 1024]);
        async_load16(g + (size_t)8 * KR, &lds[lbase + wave * 1024 + 512]);
    };

    bf16x8 a0[4], a1[4], b0[4], b1[4], s0[4], s1[4];

    // ---------------- phase 1: 8 reads -> MFMA i0..3 @ k0 ----------------
#pragma unroll
    for (int i = 0; i < 4; ++i) a0[i] = *(const bf16x8*)&lds[aB + i * 1024 + c0];
#pragma unroll
    for (int j = 0; j < 4; ++j) b0[j] = *(const bf16x8*)&lds[bB + j * 1024 + c0];
    __builtin_amdgcn_s_barrier();
    asm volatile("s_waitcnt lgkmcnt(0)" ::: "memory");
    __builtin_amdgcn_sched_barrier(0);
    __builtin_amdgcn_s_setprio(1);
#pragma unroll
    for (int i = 0; i < 4; ++i)
#pragma unroll
        for (int j = 0; j < 4; ++j)
            acc[i][j] = MFMA16(a0[i], b0[j], acc[i][j]);
    __builtin_amdgcn_s_setprio(0);

    // ---------------- phase 2: 8 reads -> MFMA i0..3 @ k1 ----------------
#pragma unroll
    for (int i = 0; i < 4; ++i) a1[i] = *(const bf16x8*)&lds[aB + i * 1024 + c1];
#pragma unroll
    for (int j = 0; j < 4; ++j) b1[j] = *(const bf16x8*)&lds[bB + j * 1024 + c1];
    __builtin_amdgcn_s_barrier();
    asm volatile("s_waitcnt lgkmcnt(0)" ::: "memory");
    __builtin_amdgcn_sched_barrier(0);
    __builtin_amdgcn_s_setprio(1);
#pragma unroll
    for (int i = 0; i < 4; ++i)
#pragma unroll
        for (int j = 0; j < 4; ++j)
            acc[i][j] = MFMA16(a1[i], b1[j], acc[i][j]);
    __builtin_amdgcn_s_setprio(0);

    // ------- phase 3: 4 reads + stage A(t+1) -> MFMA i4..7 @ k0 (b0 reuse) -------
#pragma unroll
    for (int i = 0; i < 4; ++i) s0[i] = *(const bf16x8*)&lds[aB + (4 + i) * 1024 + c0];
    if (st) {
        stage(Ab, m0,       kb1, AOFF(S ^ 1, 0));
        stage(Ab, m0 + 128, kb1, AOFF(S ^ 1, 1));
    }
    __builtin_amdgcn_s_barrier();
    asm volatile("s_waitcnt lgkmcnt(0)" ::: "memory");
    __builtin_amdgcn_sched_barrier(0);
    __builtin_amdgcn_s_setprio(1);
#pragma unroll
    for (int i = 0; i < 4; ++i)
#pragma unroll
        for (int j = 0; j < 4; ++j)
            acc[4 + i][j] = MFMA16(s0[i], b0[j], acc[4 + i][j]);
    __builtin_amdgcn_s_setprio(0);

    // ------- phase 4: 4 reads + stage B(t+1) -> MFMA i4..7 @ k1 (b1 reuse) -------
#pragma unroll
    for (int i = 0; i < 4; ++i) s1[i] = *(const bf16x8*)&lds[aB + (4 + i) * 1024 + c1];
    if (st) {
        stage(Bb, n0,       kb1, BOFF(S ^ 1, 0));
        stage(Bb, n0 + 128, kb1, BOFF(S ^ 1, 1));
    }
    __builtin_amdgcn_s_barrier();
    asm volatile("s_waitcnt lgkmcnt(0)" ::: "memory");
    __builtin_amdgcn_sched_barrier(0);
    __builtin_amdgcn_s_setprio(1);
#pragma unroll
    for (int i = 0; i < 4; ++i)
#pragma unroll
        for (int j = 0; j < 4; ++j)
            acc[4 + i][j] = MFMA16(s1[i], b1[j], acc[4 + i][j]);
    __builtin_amdgcn_s_setprio(0);

    // -------- tile end: confirm next tile's stages (depth-1 prefetch) --------
    if (st) asm volatile("s_waitcnt vmcnt(0)" ::: "memory");
    __builtin_amdgcn_s_barrier();
}

__global__ void __launch_bounds__(512, 2)
kan_gemm8(const unsigned short* __restrict__ Ab,  // (2048, 20480) bf16 basis
          const unsigned short* __restrict__ Bb,  // (1024, 20480) bf16 W
          float* __restrict__ part) {             // (KS, 2048, 1024) partials
    __shared__ __align__(16) unsigned short lds[65536];   // 128 KiB

    constexpr int KPBk   = KR / KS;          // 2560
    constexpr int NTILES = KPBk / 64;        // 40

    const int id  = blockIdx.x;
    const int z   = id & 7;                  // K-split slice -> one per XCD
    const int ord = id >> 3;                 // 0..31
    const int mt  = ord & 7;
    const int nt  = ord >> 3;                // 0..3
    const int m0  = mt * 256;
    const int n0  = nt * 256;
    const int k0  = z * KPBk;

    const int tid  = threadIdx.x;
    const int wave = tid >> 6;               // 0..7
    const int lane = tid & 63;
    const int wm   = wave >> 2;              // 0..1 -> wave owns 128 M-rows
    const int wn   = wave & 3;               // 0..3 -> wave owns 64 N-cols

    const int srow8 = lane >> 3;                    // row within 8-row chunk
    const int scol  = ((lane & 7) ^ srow8) * 8;     // pre-swizzled col offset

    auto stage = [&](const unsigned short* __restrict__ src, int grow, int kb, int lbase) {
        const unsigned short* g = src + (size_t)(grow + wave * 16 + srow8) * KR + kb + scol;
        async_load16(g,                  &lds[lbase + wave * 1024]);
        async_load16(g + (size_t)8 * KR, &lds[lbase + wave * 1024 + 512]);
    };

    f32x4 acc[8][4];
#pragma unroll
    for (int i = 0; i < 8; ++i)
#pragma unroll
        for (int j = 0; j < 4; ++j) acc[i][j] = (f32x4){0.f, 0.f, 0.f, 0.f};

    const int q   = lane >> 4;
    const int r15 = lane & 15;
    const int r7  = lane & 7;
    const int c0  = (q ^ r7) * 8;            // swizzled 16B slot, kstep 0
    const int c1  = ((4 + q) ^ r7) * 8;      // swizzled 16B slot, kstep 1

    // prologue: stage all of tile 0 into slot 0, confirm, sync
    stage(Ab, m0,       k0, AOFF(0, 0));
    stage(Ab, m0 + 128, k0, AOFF(0, 1));
    stage(Bb, n0,       k0, BOFF(0, 0));
    stage(Bb, n0 + 128, k0, BOFF(0, 1));
    asm volatile("s_waitcnt vmcnt(0)" ::: "memory");
    __builtin_amdgcn_s_barrier();

    for (int tt = 0; tt < NTILES; tt += 2) {
        tile_step<0>(tt,     NTILES, Ab, Bb, lds, acc, m0, n0, k0,
                     wave, wm, wn, r15, c0, c1, srow8, scol);
        tile_step<1>(tt + 1, NTILES, Ab, Bb, lds, acc, m0, n0, k0,
                     wave, wm, wn, r15, c0, c1, srow8, scol);
    }

    // epilogue: partials; C/D layout col=lane&15, row=(lane>>4)*4+reg
    float* dst = part + (size_t)z * OUT_ELEMS;
#pragma unroll
    for (int i = 0; i < 8; ++i)
#pragma unroll
        for (int j = 0; j < 4; ++j)
#pragma unroll
            for (int r = 0; r < 4; ++r) {
                const int row = m0 + wm * 128 + i * 16 + q * 4 + r;
                const int c   = n0 + wn * 64  + j * 16 + r15;
                dst[(size_t)row * OUT_DIM + c] = acc[i][j][r];
            }
}

// ---------------- reduce KS partial slices -> out ----------------------------
template <int KSr>
__global__ void kan_reduce(const float* __restrict__ part, float* __restrict__ out) {
    const int idx = (blockIdx.x * 256 + threadIdx.x) * 4;
    f32x4 s = *(const f32x4*)(part + idx);
#pragma unroll
    for (int z = 1; z < KSr; ++z)
        s += *(const f32x4*)(part + (size_t)z * OUT_ELEMS + idx);
    *(f32x4*)(out + idx) = s;
}

// ---------------- fallback (ws too small): correctness-only fp32 -------------
__global__ void kan_fallback(const float* __restrict__ x,
                             const float* __restrict__ W,
                             const float* __restrict__ knots,
                             float* __restrict__ out) {
    __shared__ float basis[256 * K_KNOTS];
    const int b = blockIdx.x;
    const int o = blockIdx.y * blockDim.x + threadIdx.x;
    const float invh = 1.0f / (knots[1] - knots[0]);
    const float* w = W + (size_t)o * KR;
    float sum = 0.f;
    for (int i0 = 0; i0 < IN_DIM; i0 += 256) {
        __syncthreads();
        for (int idx = threadIdx.x; idx < 256 * K_KNOTS; idx += blockDim.x) {
            const int i = i0 + idx / K_KNOTS;
            const int k = idx % K_KNOTS;
            const float d = (x[(size_t)b * IN_DIM + i] - knots[k]) * invh;
            basis[idx] = __expf(-0.5f * d * d);
        }
        __syncthreads();
        for (int r = 0; r < 256 * K_KNOTS; ++r)
            sum += basis[r] * w[(size_t)i0 * K_KNOTS + r];
    }
    out[(size_t)b * OUT_DIM + o] = sum;
}

extern "C" void kernel_launch(void* const* d_in, const int* in_sizes, int n_in,
                              void* d_out, int out_size, void* d_ws, size_t ws_size,
                              hipStream_t stream) {
    const float* x     = (const float*)d_in[0];
    const float* W     = (const float*)d_in[1];
    const float* knots = (const float*)d_in[2];
    float* out = (float*)d_out;

    const size_t basis_bytes = (size_t)B_DIM * KR * 2;              // 80 MiB
    const size_t wb_bytes    = (size_t)OUT_DIM * KR * 2;            // 40 MiB
    const size_t part_bytes  = (size_t)KS * OUT_ELEMS * 4;          // 64 MiB

    unsigned short* Ab = (unsigned short*)d_ws;
    unsigned short* Bb = (unsigned short*)((char*)d_ws + basis_bytes);
    float* part = (float*)((char*)d_ws + basis_bytes + wb_bytes);

    if (ws_size >= basis_bytes + wb_bytes + part_bytes) {
        // main path: vectorized prep + R3 gemm + reduce. 3 dispatches.
        prep_kernel<<<dim3(NB_BASIS_BLK + NB_W_BLK), dim3(256), 0, stream>>>(
            x, (const float4*)W, knots, (uint4*)Ab, (uint4*)Bb);
        kan_gemm8<<<dim3(256), dim3(512), 0, stream>>>(Ab, Bb, part);
        kan_reduce<KS><<<dim3(OUT_ELEMS / (256 * 4)), dim3(256), 0, stream>>>(part, out);
    } else {
        kan_fallback<<<dim3(B_DIM, OUT_DIM / 256), dim3(256), 0, stream>>>(x, W, knots, out);
    }
}